// Round 12
// baseline (179.660 us; speedup 1.0000x reference)
//
#include <hip/hip_runtime.h>
#include <hip/hip_bf16.h>

#define BINS 100
#define DIM 768
#define TPB 64        // tokens per block
#define NTHREADS 256
#define KPAD 128      // BINS padded to MFMA K multiple
#define PITCH 136     // ushort pitch for wbf rows: 272B, 16B-aligned

// workspace byte offsets
#define OFF_ET   0         // ushort[768*128] = 196608 B
#define OFF_P    196608    // float[100] (512 B reserved)
#define OFF_Q    197120
#define OFF_TS   197632
#define OFF_KS   198144    // int[100]
#define OFF_R    198656    // int
#define OFF_W2P  198720    // float[100*100] = 40000 B (end 238720)

typedef __attribute__((ext_vector_type(8))) short bf16x8;
typedef __attribute__((ext_vector_type(4))) float f32x4;
typedef __attribute__((ext_vector_type(16))) float f32x16;

__device__ __forceinline__ unsigned short f2bf(float x) {
    __hip_bfloat16 h = __float2bfloat16(x);
    return *reinterpret_cast<unsigned short*>(&h);
}
__device__ __forceinline__ float bfrt(float x) {   // bf16 round-trip (RNE)
    return __bfloat162float(__float2bfloat16(x));
}
__device__ __forceinline__ f32x4 bfrt4(f32x4 v) {
    f32x4 r;
    r.x = bfrt(v.x); r.y = bfrt(v.y); r.z = bfrt(v.z); r.w = bfrt(v.w);
    return r;
}

// grid = DIM+1 blocks x 128 threads. Blocks [0,DIM): transpose emb -> bf16 ET.
// Block DIM: build P,Q (collapsed linear map), w2p = w2 + I, sorted thresholds.
__global__ void prep(const float* __restrict__ emb,
                     const float* __restrict__ w1,
                     const float* __restrict__ b1,
                     const float* __restrict__ w2,
                     const float* __restrict__ b2,
                     unsigned char* __restrict__ ws)
{
    const int bid = blockIdx.x;
    const int tid = threadIdx.x;
    if (bid < DIM) {
        unsigned short* et = (unsigned short*)(ws + OFF_ET);
        float v = (tid < BINS) ? emb[(long)tid * DIM + bid] : 0.f;
        et[bid * KPAD + tid] = f2bf(v);
        return;
    }
    __shared__ float pl[BINS], ql[BINS], tl[BINS];
    float* Pv  = (float*)(ws + OFF_P);
    float* Qv  = (float*)(ws + OFF_Q);
    float* ts  = (float*)(ws + OFF_TS);
    int*   ks  = (int*)  (ws + OFF_KS);
    int*   Rp  = (int*)  (ws + OFF_R);
    float* w2p = (float*)(ws + OFF_W2P);
    if (tid < BINS) {
        float w = w1[tid], b = b1[tid];
        // branch taken as x -> +inf (the "common" branch for x in [0,10])
        float f = (w > 0.f || (w == 0.f && b > 0.f)) ? 1.f : 0.1f;
        pl[tid] = w * f;
        ql[tid] = b * f;
        tl[tid] = (w != 0.f) ? (-b / w) : -1.f;   // breakpoint; w==0 never flips
    }
    __syncthreads();
    if (tid < BINS) {
        const int j = tid;
        float P = pl[j];            // alpha=1 direct term
        float Q = ql[j] + b2[j];
        for (int k = 0; k < BINS; k++) {
            float w = w2[j * BINS + k];
            P = fmaf(w, pl[k], P);
            Q = fmaf(w, ql[k], Q);
            w2p[j * BINS + k] = w + (j == k ? 1.f : 0.f);   // matmul + alpha*I
        }
        Pv[j] = P; Qv[j] = Q;
        // rank-sort thresholds descending
        float tk = tl[j];
        int rank = 0;
        for (int k2 = 0; k2 < BINS; k2++) {
            float t2 = tl[k2];
            rank += (t2 > tk || (t2 == tk && k2 < j)) ? 1 : 0;
        }
        ts[rank] = tk;
        ks[rank] = j;
    }
    if (tid == 0) {
        int R = 0;
        for (int k = 0; k < BINS; k++) R += (tl[k] > 0.f) ? 1 : 0;
        *Rp = R;
    }
}

__global__ __launch_bounds__(NTHREADS, 8)
void ead_kernel(const float* __restrict__ gene,
                const int*   __restrict__ pad_mask,
                const int*   __restrict__ masked_mask,
                const float* __restrict__ w1,
                const float* __restrict__ b1,
                const unsigned short* __restrict__ et,
                const float* __restrict__ Pv,
                const float* __restrict__ Qv,
                const float* __restrict__ ts,
                const int*   __restrict__ ksod,
                const int*   __restrict__ Rp,
                const float* __restrict__ w2p,
                const float* __restrict__ pad_emb,
                const float* __restrict__ mask_emb,
                float* __restrict__ out,
                int T)
{
    __shared__ unsigned short wbf[TPB][PITCH]; // bf16 softmax weights, K-padded
    __shared__ float xs[TPB];
    __shared__ short surv[TPB];
    __shared__ short olist[TPB];   // row | (is_mask << 8)
    __shared__ int Ssh, Osh;

    const int tid  = threadIdx.x;
    const int lane = tid & 63;
    const int wave = tid >> 6;

    // XCD-bijective swizzle: consecutive output regions stay on one XCD's L2.
    const int nblk = (int)gridDim.x;
    const int bid  = (int)blockIdx.x;
    const int wg   = ((nblk & 7) == 0) ? ((bid & 7) * (nblk >> 3) + (bid >> 3))
                                       : bid;
    const long t0  = (long)wg * TPB;
    const int nvalid = min(TPB, (int)(T - t0));

    // ---- step 1: masks, survivor + override compaction (wave 0) ----
    if (wave == 0) {
        int o = 3; // out-of-range: neither computed nor written
        if (lane < nvalid) {
            int pm  = pad_mask[t0 + lane];
            int msk = masked_mask[t0 + lane];
            o = msk ? 2 : (pm ? 1 : 0);
            xs[lane] = gene[t0 + lane];
        }
        unsigned long long bs = __ballot(o == 0);
        unsigned long long bo = __ballot(o == 1 || o == 2);
        int si = __popcll(bs & ((1ull << lane) - 1ull));
        int oi = __popcll(bo & ((1ull << lane) - 1ull));
        if (o == 0) surv[si] = (short)lane;
        if (o == 1 || o == 2) olist[oi] = (short)(lane | ((o == 2) ? 256 : 0));
        if (lane == 0) { Ssh = __popcll(bs); Osh = __popcll(bo); }
    }
    __syncthreads();
    const int S = Ssh, O = Osh;

    // ---- step 1.5: override rows, row-per-wave, full 3KB/row from registers ----
    // Plain stores (NT removed this round: isolate the nt flag's BW effect).
    {
        const f32x4* pe = (const f32x4*)pad_emb;
        const f32x4* me = (const f32x4*)mask_emb;
        f32x4 p0 = bfrt4(pe[lane]), p1 = bfrt4(pe[lane + 64]), p2 = bfrt4(pe[lane + 128]);
        f32x4 m0 = bfrt4(me[lane]), m1 = bfrt4(me[lane + 64]), m2 = bfrt4(me[lane + 128]);
        for (int i = wave; i < O; i += 4) {
            int e = olist[i];
            int row = e & 63;
            bool mm = (e & 256) != 0;
            f32x4* orow = (f32x4*)(out + (t0 + row) * (long)DIM);
            orow[lane]       = mm ? m0 : p0;
            orow[lane + 64]  = mm ? m1 : p1;
            orow[lane + 128] = mm ? m2 : p2;
        }
    }

    // ---- steps 2-4 collapsed: v3 = x*P + Q + rare-bin corrections; softmax ----
    // slot s = wave + 4*(lane>>2): spreads slots across all 4 waves/SIMDs;
    // 4-lane shuffle partners stay within the wave.
    {
        int s = wave + 4 * (lane >> 2);
        int part = lane & 3;
        const int j0 = part * 25;
        if (s < S) {
            float x = xs[surv[s]];
            float v3[25];
            #pragma unroll
            for (int i = 0; i < 25; i++)
                v3[i] = fmaf(x, Pv[j0 + i], Qv[j0 + i]);
            const int R = *Rp;
            for (int idx = 0; idx < R; ++idx) {
                float t = ts[idx];
                if (t <= x) break;              // sorted desc: rest are common
                int k = ksod[idx];
                float v1 = fmaf(x, w1[k], b1[k]);
                float d = 0.9f * fabsf(v1);     // (f_actual - f_common)*v1
                const float* wc = w2p + j0 * BINS + k;
                #pragma unroll
                for (int i = 0; i < 25; i++)
                    v3[i] = fmaf(wc[i * BINS], d, v3[i]);
            }
            float vmax = -1e30f;
            #pragma unroll
            for (int i = 0; i < 25; i++) vmax = fmaxf(vmax, v3[i]);
            vmax = fmaxf(vmax, __shfl_xor(vmax, 1));
            vmax = fmaxf(vmax, __shfl_xor(vmax, 2));
            float sum = 0.f;
            #pragma unroll
            for (int i = 0; i < 25; i++) {
                v3[i] = __expf(v3[i] - vmax);
                sum += v3[i];
            }
            sum += __shfl_xor(sum, 1);
            sum += __shfl_xor(sum, 2);
            float inv = 1.f / sum;
            #pragma unroll
            for (int i = 0; i < 25; i++)
                wbf[s][j0 + i] = f2bf(v3[i] * inv);
            if (part == 3) {
                #pragma unroll
                for (int j = BINS; j < KPAD; j += 2)
                    *reinterpret_cast<unsigned int*>(&wbf[s][j]) = 0u;
            }
        }
    }
    __syncthreads();

    // ---- step 5: MFMA 32x32x16: D[slot][d] = W(S x K) · ET^T(K x d) ----
    // C/D layout (verified, m74/m101): col=lane&31, row=(reg&3)+8*(reg>>2)+4*(lane>>5).
    // A and B loaded with the SAME k-mapping k = ks*16 + (lane>>5)*8 + j, so any
    // bijective hw k-permutation cancels. One store instruction = 2 rows x 128B
    // fully-covered lines. et read in a single pass per block.
    if (S > 0) {
        const int col  = lane & 31;     // A-row (slot) and B-col (d) and D-col
        const int half = lane >> 5;
        const int nmt = (S > 32) ? 2 : 1;
        for (int mtile = 0; mtile < nmt; mtile++) {
            for (int ct = 0; ct < 6; ct++) {
                int cbase = (wave * 6 + ct) * 32;
                const unsigned short* bp = et + (long)(cbase + col) * KPAD + half * 8;
                f32x16 acc;
                #pragma unroll
                for (int r = 0; r < 16; r++) acc[r] = 0.f;
                #pragma unroll
                for (int ks = 0; ks < 8; ks++) {
                    bf16x8 afr = *(const bf16x8*)&wbf[mtile * 32 + col][ks * 16 + half * 8];
                    bf16x8 bfr = *(const bf16x8*)(bp + ks * 16);
                    acc = __builtin_amdgcn_mfma_f32_32x32x16_bf16(afr, bfr, acc, 0, 0, 0);
                }
                #pragma unroll
                for (int r = 0; r < 16; r++) {
                    int row = (r & 3) + 8 * (r >> 2) + 4 * half + mtile * 32;
                    if (row < S) {
                        int tkn = surv[row];
                        out[(t0 + tkn) * (long)DIM + cbase + col] = acc[r];
                    }
                }
            }
        }
    }
}

extern "C" void kernel_launch(void* const* d_in, const int* in_sizes, int n_in,
                              void* d_out, int out_size, void* d_ws, size_t ws_size,
                              hipStream_t stream) {
    const float* gene  = (const float*)d_in[0];
    const int*   pm    = (const int*)  d_in[1];
    const int*   mm    = (const int*)  d_in[2];
    const float* w1    = (const float*)d_in[3];
    const float* b1    = (const float*)d_in[4];
    const float* w2    = (const float*)d_in[5];
    const float* b2    = (const float*)d_in[6];
    const float* emb   = (const float*)d_in[7];
    const float* pade  = (const float*)d_in[8];
    const float* maske = (const float*)d_in[9];
    float* out = (float*)d_out;
    unsigned char* ws = (unsigned char*)d_ws;

    int T = in_sizes[0];                          // 8 * 19264 = 154112 tokens
    int nblk = (T + TPB - 1) / TPB;               // 2408 (divisible by 8)

    hipLaunchKernelGGL(prep, dim3(DIM + 1), dim3(KPAD), 0, stream,
                       emb, w1, b1, w2, b2, ws);
    hipLaunchKernelGGL(ead_kernel, dim3(nblk), dim3(NTHREADS), 0, stream,
                       gene, pm, mm, w1, b1,
                       (const unsigned short*)(ws + OFF_ET),
                       (const float*)(ws + OFF_P),
                       (const float*)(ws + OFF_Q),
                       (const float*)(ws + OFF_TS),
                       (const int*)(ws + OFF_KS),
                       (const int*)(ws + OFF_R),
                       (const float*)(ws + OFF_W2P),
                       pade, maske, out, T);
}

// Round 13
// 146.879 us; speedup vs baseline: 1.2232x; 1.2232x over previous
//
#include <hip/hip_runtime.h>
#include <hip/hip_bf16.h>

#define BINS 100
#define DIM 768
#define TPB 64        // tokens per block
#define NTHREADS 256
#define KPAD 128      // BINS padded to MFMA K multiple
#define PITCH 136     // ushort pitch for wbf rows: 272B, 16B-aligned

// workspace byte offsets
#define OFF_ET    0        // ushort[768*128] = 196608 B
#define OFF_P     196608   // float[100] (512 B reserved)
#define OFF_Q     197120   // float[100] (512 B reserved)
#define OFF_RARE  197632   // float4[104] = 1664 B (2048 reserved)
#define OFF_R     199680   // int (64 B reserved)
#define OFF_W2PT  199744   // float[100*100] = 40000 B (end 239744)

typedef __attribute__((ext_vector_type(8))) short bf16x8;
typedef __attribute__((ext_vector_type(4))) float f32x4;
typedef __attribute__((ext_vector_type(16))) float f32x16;

__device__ __forceinline__ unsigned short f2bf(float x) {
    __hip_bfloat16 h = __float2bfloat16(x);
    return *reinterpret_cast<unsigned short*>(&h);
}
__device__ __forceinline__ float bfrt(float x) {   // bf16 round-trip (RNE)
    return __bfloat162float(__float2bfloat16(x));
}
__device__ __forceinline__ f32x4 bfrt4(f32x4 v) {
    f32x4 r;
    r.x = bfrt(v.x); r.y = bfrt(v.y); r.z = bfrt(v.z); r.w = bfrt(v.w);
    return r;
}

// grid = DIM+1 blocks x 128 threads. Blocks [0,DIM): transpose emb -> bf16 ET.
// Block DIM: build P,Q (collapsed linear map), w2pT = (w2 + I)^T (row k
// contiguous in j), packed rare table {t, w1[k], b1[k], k} sorted by t desc.
__global__ void prep(const float* __restrict__ emb,
                     const float* __restrict__ w1,
                     const float* __restrict__ b1,
                     const float* __restrict__ w2,
                     const float* __restrict__ b2,
                     unsigned char* __restrict__ ws)
{
    const int bid = blockIdx.x;
    const int tid = threadIdx.x;
    if (bid < DIM) {
        unsigned short* et = (unsigned short*)(ws + OFF_ET);
        float v = (tid < BINS) ? emb[(long)tid * DIM + bid] : 0.f;
        et[bid * KPAD + tid] = f2bf(v);
        return;
    }
    __shared__ float pl[BINS], ql[BINS], tl[BINS];
    float* Pv   = (float*)(ws + OFF_P);
    float* Qv   = (float*)(ws + OFF_Q);
    f32x4* rare = (f32x4*)(ws + OFF_RARE);
    int*   Rp   = (int*)  (ws + OFF_R);
    float* w2pT = (float*)(ws + OFF_W2PT);
    if (tid < BINS) {
        float w = w1[tid], b = b1[tid];
        // branch taken as x -> +inf (the "common" branch for x in [0,10])
        float f = (w > 0.f || (w == 0.f && b > 0.f)) ? 1.f : 0.1f;
        pl[tid] = w * f;
        ql[tid] = b * f;
        tl[tid] = (w != 0.f) ? (-b / w) : -1.f;   // breakpoint; w==0 never flips
    }
    __syncthreads();
    if (tid < BINS) {
        const int j = tid;
        float P = pl[j];            // alpha=1 direct term
        float Q = ql[j] + b2[j];
        for (int k = 0; k < BINS; k++) {
            float w = w2[j * BINS + k];
            P = fmaf(w, pl[k], P);
            Q = fmaf(w, ql[k], Q);
            // transposed: row k contiguous in j -> coalesced correction reads
            w2pT[k * BINS + j] = w + (j == k ? 1.f : 0.f);
        }
        Pv[j] = P; Qv[j] = Q;
        // rank-sort thresholds descending; pack rare-walk data into one float4
        float tk = tl[tid];
        int rank = 0;
        for (int k2 = 0; k2 < BINS; k2++) {
            float t2 = tl[k2];
            rank += (t2 > tk || (t2 == tk && k2 < tid)) ? 1 : 0;
        }
        f32x4 e;
        e.x = tk; e.y = w1[tid]; e.z = b1[tid];
        e.w = __int_as_float(tid);
        rare[rank] = e;
    }
    if (tid == 0) {
        int R = 0;
        for (int k = 0; k < BINS; k++) R += (tl[k] > 0.f) ? 1 : 0;
        *Rp = R;
        // sentinel so idx+0 load at idx==R is always valid & terminates
        f32x4 s; s.x = -1e30f; s.y = 0.f; s.z = 0.f; s.w = __int_as_float(0);
        rare[BINS] = s;
    }
}

__global__ __launch_bounds__(NTHREADS, 8)
void ead_kernel(const float* __restrict__ gene,
                const int*   __restrict__ pad_mask,
                const int*   __restrict__ masked_mask,
                const unsigned short* __restrict__ et,
                const float* __restrict__ Pv,
                const float* __restrict__ Qv,
                const f32x4* __restrict__ rare,
                const int*   __restrict__ Rp,
                const float* __restrict__ w2pT,
                const float* __restrict__ pad_emb,
                const float* __restrict__ mask_emb,
                float* __restrict__ out,
                int T)
{
    __shared__ unsigned short wbf[TPB][PITCH]; // bf16 softmax weights, K-padded
    __shared__ float xs[TPB];
    __shared__ short surv[TPB];
    __shared__ short olist[TPB];   // row | (is_mask << 8)
    __shared__ int Ssh, Osh;

    const int tid  = threadIdx.x;
    const int lane = tid & 63;
    const int wave = tid >> 6;

    // XCD-bijective swizzle: consecutive output regions stay on one XCD's L2.
    const int nblk = (int)gridDim.x;
    const int bid  = (int)blockIdx.x;
    const int wg   = ((nblk & 7) == 0) ? ((bid & 7) * (nblk >> 3) + (bid >> 3))
                                       : bid;
    const long t0  = (long)wg * TPB;
    const int nvalid = min(TPB, (int)(T - t0));

    // ---- step 1: masks, survivor + override compaction (wave 0) ----
    if (wave == 0) {
        int o = 3; // out-of-range: neither computed nor written
        if (lane < nvalid) {
            int pm  = pad_mask[t0 + lane];
            int msk = masked_mask[t0 + lane];
            o = msk ? 2 : (pm ? 1 : 0);
            xs[lane] = gene[t0 + lane];
        }
        unsigned long long bs = __ballot(o == 0);
        unsigned long long bo = __ballot(o == 1 || o == 2);
        int si = __popcll(bs & ((1ull << lane) - 1ull));
        int oi = __popcll(bo & ((1ull << lane) - 1ull));
        if (o == 0) surv[si] = (short)lane;
        if (o == 1 || o == 2) olist[oi] = (short)(lane | ((o == 2) ? 256 : 0));
        if (lane == 0) { Ssh = __popcll(bs); Osh = __popcll(bo); }
    }
    __syncthreads();
    const int S = Ssh, O = Osh;

    // ---- step 1.5: override rows, row-per-wave, NT streaming stores ----
    // (r12 A/B: NT = -28 us; keeps 355 MB of pad/mask lines out of L2.)
    {
        const f32x4* pe = (const f32x4*)pad_emb;
        const f32x4* me = (const f32x4*)mask_emb;
        f32x4 p0 = bfrt4(pe[lane]), p1 = bfrt4(pe[lane + 64]), p2 = bfrt4(pe[lane + 128]);
        f32x4 m0 = bfrt4(me[lane]), m1 = bfrt4(me[lane + 64]), m2 = bfrt4(me[lane + 128]);
        for (int i = wave; i < O; i += 4) {
            int e = olist[i];
            int row = e & 63;
            bool mm = (e & 256) != 0;
            f32x4* orow = (f32x4*)(out + (t0 + row) * (long)DIM);
            __builtin_nontemporal_store(mm ? m0 : p0, orow + lane);
            __builtin_nontemporal_store(mm ? m1 : p1, orow + lane + 64);
            __builtin_nontemporal_store(mm ? m2 : p2, orow + lane + 128);
        }
    }

    // ---- steps 2-4 collapsed: v3 = x*P + Q + rare-bin corrections; softmax ----
    // Rare walk: ONE float4 load per iteration (packed {t,w1,b1,k}); correction
    // row w2pT[k][j0..j0+24] is CONTIGUOUS (4-lane group covers 400B span).
    {
        int s = wave + 4 * (lane >> 2);
        int part = lane & 3;
        const int j0 = part * 25;
        if (s < S) {
            float x = xs[surv[s]];
            float v3[25];
            #pragma unroll
            for (int i = 0; i < 25; i++)
                v3[i] = fmaf(x, Pv[j0 + i], Qv[j0 + i]);
            const int R = *Rp;
            for (int idx = 0; idx < R; ++idx) {
                f32x4 rr = rare[idx];
                if (rr.x <= x) break;           // sorted desc: rest are common
                float v1 = fmaf(x, rr.y, rr.z);
                float d = 0.9f * fabsf(v1);     // (f_actual - f_common)*v1
                int k = __float_as_int(rr.w);
                const float* wc = w2pT + k * BINS + j0;
                #pragma unroll
                for (int i = 0; i < 25; i++)
                    v3[i] = fmaf(wc[i], d, v3[i]);
            }
            float vmax = -1e30f;
            #pragma unroll
            for (int i = 0; i < 25; i++) vmax = fmaxf(vmax, v3[i]);
            vmax = fmaxf(vmax, __shfl_xor(vmax, 1));
            vmax = fmaxf(vmax, __shfl_xor(vmax, 2));
            float sum = 0.f;
            #pragma unroll
            for (int i = 0; i < 25; i++) {
                v3[i] = __expf(v3[i] - vmax);
                sum += v3[i];
            }
            sum += __shfl_xor(sum, 1);
            sum += __shfl_xor(sum, 2);
            float inv = 1.f / sum;
            #pragma unroll
            for (int i = 0; i < 25; i++)
                wbf[s][j0 + i] = f2bf(v3[i] * inv);
            if (part == 3) {
                #pragma unroll
                for (int j = BINS; j < KPAD; j += 2)
                    *reinterpret_cast<unsigned int*>(&wbf[s][j]) = 0u;
            }
        }
    }
    __syncthreads();

    // ---- step 5: MFMA 32x32x16: D[slot][d] = W(S x K) · ET^T(K x d) ----
    // C/D layout (verified): col=lane&31, row=(reg&3)+8*(reg>>2)+4*(lane>>5).
    // A and B use the SAME k-mapping k = ks*16 + half*8 + j (hw k-perm cancels).
    // One store instruction = 2 rows x 128B fully-covered lines.
    // A-frags (wbf) depend only on (mtile,ks) -> hoisted out of the ct loop:
    // 8 LDS reads per mtile instead of 48.
    if (S > 0) {
        const int col  = lane & 31;     // A-row (slot) / B,D-col (d)
        const int half = lane >> 5;
        const int nmt = (S > 32) ? 2 : 1;
        for (int mtile = 0; mtile < nmt; mtile++) {
            const unsigned short* arow = &wbf[mtile * 32 + col][half * 8];
            bf16x8 a0 = *(const bf16x8*)(arow);
            bf16x8 a1 = *(const bf16x8*)(arow + 16);
            bf16x8 a2 = *(const bf16x8*)(arow + 32);
            bf16x8 a3 = *(const bf16x8*)(arow + 48);
            bf16x8 a4 = *(const bf16x8*)(arow + 64);
            bf16x8 a5 = *(const bf16x8*)(arow + 80);
            bf16x8 a6 = *(const bf16x8*)(arow + 96);
            bf16x8 a7 = *(const bf16x8*)(arow + 112);
            for (int ct = 0; ct < 6; ct++) {
                int cbase = (wave * 6 + ct) * 32;
                const unsigned short* bp = et + (long)(cbase + col) * KPAD + half * 8;
                f32x16 acc;
                #pragma unroll
                for (int r = 0; r < 16; r++) acc[r] = 0.f;
                acc = __builtin_amdgcn_mfma_f32_32x32x16_bf16(a0, *(const bf16x8*)(bp),       acc, 0, 0, 0);
                acc = __builtin_amdgcn_mfma_f32_32x32x16_bf16(a1, *(const bf16x8*)(bp + 16),  acc, 0, 0, 0);
                acc = __builtin_amdgcn_mfma_f32_32x32x16_bf16(a2, *(const bf16x8*)(bp + 32),  acc, 0, 0, 0);
                acc = __builtin_amdgcn_mfma_f32_32x32x16_bf16(a3, *(const bf16x8*)(bp + 48),  acc, 0, 0, 0);
                acc = __builtin_amdgcn_mfma_f32_32x32x16_bf16(a4, *(const bf16x8*)(bp + 64),  acc, 0, 0, 0);
                acc = __builtin_amdgcn_mfma_f32_32x32x16_bf16(a5, *(const bf16x8*)(bp + 80),  acc, 0, 0, 0);
                acc = __builtin_amdgcn_mfma_f32_32x32x16_bf16(a6, *(const bf16x8*)(bp + 96),  acc, 0, 0, 0);
                acc = __builtin_amdgcn_mfma_f32_32x32x16_bf16(a7, *(const bf16x8*)(bp + 112), acc, 0, 0, 0);
                #pragma unroll
                for (int r = 0; r < 16; r++) {
                    int row = (r & 3) + 8 * (r >> 2) + 4 * half + mtile * 32;
                    if (row < S) {
                        int tkn = surv[row];
                        out[(t0 + tkn) * (long)DIM + cbase + col] = acc[r];
                    }
                }
            }
        }
    }
}

extern "C" void kernel_launch(void* const* d_in, const int* in_sizes, int n_in,
                              void* d_out, int out_size, void* d_ws, size_t ws_size,
                              hipStream_t stream) {
    const float* gene  = (const float*)d_in[0];
    const int*   pm    = (const int*)  d_in[1];
    const int*   mm    = (const int*)  d_in[2];
    const float* w1    = (const float*)d_in[3];
    const float* b1    = (const float*)d_in[4];
    const float* w2    = (const float*)d_in[5];
    const float* b2    = (const float*)d_in[6];
    const float* emb   = (const float*)d_in[7];
    const float* pade  = (const float*)d_in[8];
    const float* maske = (const float*)d_in[9];
    float* out = (float*)d_out;
    unsigned char* ws = (unsigned char*)d_ws;

    int T = in_sizes[0];                          // 8 * 19264 = 154112 tokens
    int nblk = (T + TPB - 1) / TPB;               // 2408 (divisible by 8)

    hipLaunchKernelGGL(prep, dim3(DIM + 1), dim3(KPAD), 0, stream,
                       emb, w1, b1, w2, b2, ws);
    hipLaunchKernelGGL(ead_kernel, dim3(nblk), dim3(NTHREADS), 0, stream,
                       gene, pm, mm,
                       (const unsigned short*)(ws + OFF_ET),
                       (const float*)(ws + OFF_P),
                       (const float*)(ws + OFF_Q),
                       (const f32x4*)(ws + OFF_RARE),
                       (const int*)(ws + OFF_R),
                       (const float*)(ws + OFF_W2PT),
                       pade, maske, out, T);
}